// Round 11
// baseline (98.405 us; speedup 1.0000x reference)
//
#include <hip/hip_runtime.h>

#define DEVI __device__ __forceinline__

typedef unsigned short u16;
typedef unsigned int   u32;
typedef unsigned long long u64;
typedef float  f32x4  __attribute__((ext_vector_type(4)));
typedef __bf16 bf16x8 __attribute__((ext_vector_type(8)));

union FragU { bf16x8 b; u64 u[2]; __bf16 e[8]; };

DEVI u16 f2b(float x) { __bf16 t = (__bf16)x; return __builtin_bit_cast(u16, t); }

DEVI float exp2a(float x) { float r; asm("v_exp_f32 %0, %1" : "=v"(r) : "v"(x)); return r; }

DEVI void gload16(const void* g, void* l) {
  __builtin_amdgcn_global_load_lds((const __attribute__((address_space(1))) u32*)g,
                                   (__attribute__((address_space(3))) u32*)l, 16, 0, 0);
}

// k-bit-permutation within a 128B chunk: makes MFMA fragment (ks,u) bytes contiguous.
// old bits [6]=ks [5]=hi [4:3]=u [2:0]=lo  ->  new: ks | u<<4 | hi<<3 | lo
DEVI int kperm(int b) {
  return (b & 0x47) | ((b & 0x18) << 1) | ((b & 0x20) >> 2);
}
// producer-side swizzled offset within one [row][128B] chunk: perm + granule XOR
DEVI int swzo(int row, int b) {
  const int p = kperm(b);
  return ((((p >> 4) ^ row) & 7) << 4) | (p & 15);
}
// consumer: single ds_read_b128 of fragment granule g = ks*4+u
DEVI FragU ldfrag(const char* base, int row, int g) {
  return *reinterpret_cast<const FragU*>(base + row * 128 + (((g ^ (row & 7)) << 4)));
}
// producer-side global address: linear rows of `rowbytes`, swizzled within each 128B chunk
DEVI size_t gaddr(int row, int kbyte, int rowbytes) {
  return (size_t)row * rowbytes + (size_t)((kbyte & ~127) + swzo(row, kbyte & 127));
}

// ---------------- prep: 6 weight transposes + LN1, one kernel ----------------
__global__ __launch_bounds__(256)
void prep(const float* __restrict__ Wq, const float* __restrict__ Wk,
          const float* __restrict__ Wv, const float* __restrict__ Wo,
          const float* __restrict__ W1, const float* __restrict__ W2,
          u16* __restrict__ wqkvT, u16* __restrict__ woT,
          u16* __restrict__ w1T, u16* __restrict__ w2T,
          const float* __restrict__ y, const float* __restrict__ ln1g,
          const float* __restrict__ ln1b, char* __restrict__ xb) {
  const int id = blockIdx.x;
  if (id < 2048) {
    __shared__ float tile[32][33];
    const float* src; u16* dst; int K, N, bx, by;
    if (id < 1024) {
      const int m = id >> 8, t = id & 255;
      K = 512; N = 512; bx = t & 15; by = t >> 4;
      src = (m == 0) ? Wq : (m == 1) ? Wk : (m == 2) ? Wv : Wo;
      dst = (m == 3) ? woT : wqkvT + m * 512 * 512;
    } else if (id < 1536) {
      const int t = id - 1024; K = 512; N = 1024; bx = t & 31; by = t >> 5;
      src = W1; dst = w1T;
    } else {
      const int t = id - 1536; K = 1024; N = 512; bx = t & 15; by = t >> 4;
      src = W2; dst = w2T;
    }
    const int tx = threadIdx.x & 31, ty = threadIdx.x >> 5;
#pragma unroll
    for (int i = 0; i < 4; ++i)
      tile[ty + i * 8][tx] = src[(size_t)(by * 32 + ty + i * 8) * N + bx * 32 + tx];
    __syncthreads();
    // write side: thread packs 4 consecutive k into one swizzled u64 store
    const int nl = threadIdx.x >> 3, kq = threadIdx.x & 7;
    const int n = bx * 32 + nl;
    const int kg = by * 32 + kq * 4;
    union { ushort4 s; u64 q; } pk;
    pk.s.x = f2b(tile[kq * 4 + 0][nl]);
    pk.s.y = f2b(tile[kq * 4 + 1][nl]);
    pk.s.z = f2b(tile[kq * 4 + 2][nl]);
    pk.s.w = f2b(tile[kq * 4 + 3][nl]);
    *(u64*)((char*)dst + gaddr(n, 2 * kg, 2 * K)) = pk.q;
  } else {
    const int row = id - 2048;
    const int t = threadIdx.x;
    const float2 v = ((const float2*)(y + (size_t)row * 512))[t];
    float s1 = v.x + v.y, s2 = v.x * v.x + v.y * v.y;
#pragma unroll
    for (int off = 32; off; off >>= 1) { s1 += __shfl_xor(s1, off); s2 += __shfl_xor(s2, off); }
    __shared__ float a1[4], a2[4];
    const int w = t >> 6;
    if ((t & 63) == 0) { a1[w] = s1; a2[w] = s2; }
    __syncthreads();
    s1 = a1[0] + a1[1] + a1[2] + a1[3];
    s2 = a2[0] + a2[1] + a2[2] + a2[3];
    const float mean = s1 * (1.f / 512.f);
    const float var = s2 * (1.f / 512.f) - mean * mean;
    const float rstd = rsqrtf(var + 1e-5f);
    const float2 gg = ((const float2*)ln1g)[t];
    const float2 bb = ((const float2*)ln1b)[t];
    const u16 o0 = f2b((v.x - mean) * rstd * gg.x + bb.x);
    const u16 o1 = f2b((v.y - mean) * rstd * gg.y + bb.y);
    *(u32*)(xb + gaddr(row, 4 * t, 1024)) = (u32)o0 | ((u32)o1 << 16);
  }
}

// ---------------- layernorm f32 -> bf16 (swizzled output), row = 512 ----------------
__global__ __launch_bounds__(256)
void ln_bf16(const float* __restrict__ x, const float* __restrict__ g,
             const float* __restrict__ b, char* __restrict__ out) {
  const int row = blockIdx.x;
  const int t = threadIdx.x;
  const float2 v = ((const float2*)(x + (size_t)row * 512))[t];
  float s1 = v.x + v.y, s2 = v.x * v.x + v.y * v.y;
#pragma unroll
  for (int off = 32; off; off >>= 1) { s1 += __shfl_xor(s1, off); s2 += __shfl_xor(s2, off); }
  __shared__ float a1[4], a2[4];
  const int w = t >> 6;
  if ((t & 63) == 0) { a1[w] = s1; a2[w] = s2; }
  __syncthreads();
  s1 = a1[0] + a1[1] + a1[2] + a1[3];
  s2 = a2[0] + a2[1] + a2[2] + a2[3];
  const float mean = s1 * (1.f / 512.f);
  const float var = s2 * (1.f / 512.f) - mean * mean;
  const float rstd = rsqrtf(var + 1e-5f);
  const float2 gg = ((const float2*)g)[t];
  const float2 bb = ((const float2*)b)[t];
  const u16 o0 = f2b((v.x - mean) * rstd * gg.x + bb.x);
  const u16 o1 = f2b((v.y - mean) * rstd * gg.y + bb.y);
  *(u32*)(out + gaddr(row, 4 * t, 1024)) = (u32)o0 | ((u32)o1 << 16);
}

// ---------------- GEMM: C = A[M][K] @ Bt[N][K]^T ----------------
enum { EPI_QKV = 0, EPI_RES = 1, EPI_GELU = 2 };

template <int EPI, int WM, int WN, int AM, int AN>
__global__ __launch_bounds__(WM * WN * 64)
void gemm_bf16(const char* __restrict__ A, const char* __restrict__ Bt, int N, int K,
               const float* __restrict__ bias,
               const float* __restrict__ bq, const float* __restrict__ bk,
               const float* __restrict__ bv,
               const float* __restrict__ res, float* __restrict__ outF,
               char* __restrict__ outB,
               u16* __restrict__ qo, char* __restrict__ ko, char* __restrict__ vo) {
  constexpr int NW = WM * WN;
  constexpr int TM = WM * AM * 16, TN = WN * AN * 16;
  constexpr int NCHA = TM / 8, NCHB = TN / 8, NCH = NCHA + NCHB;
  constexpr int CPW = NCH / NW;
  static_assert(CPW * NW == NCH, "chunk split");
  __shared__ __align__(16) char sA[2][TM * 128];
  __shared__ __align__(16) char sB[2][TN * 128];
  const int tid = threadIdx.x;
  const int l = tid & 63, w = tid >> 6;
  const int tm = blockIdx.x, tn = blockIdx.y;
  const int wr = w / WN, wc = w % WN;
  const int u = l >> 4, r16 = l & 15;
  const int lrow = l >> 3, lgr = l & 7;
  f32x4 acc[AM][AN] = {};
  const size_t KB = (size_t)K * 2;
  const char* Ab = A + (size_t)(tm * TM) * KB;
  const char* Bb = Bt + (size_t)(tn * TN) * KB;
  const int nkt = K >> 6;
  auto stage = [&](int buf, int kt) {
#pragma unroll
    for (int i = 0; i < CPW; ++i) {
      const int c = w * CPW + i;
      if (c < NCHA) {
        gload16(Ab + (size_t)(c * 8 + lrow) * KB + (size_t)kt * 128 + (lgr << 4),
                sA[buf] + c * 1024);
      } else {
        const int c2 = c - NCHA;
        gload16(Bb + (size_t)(c2 * 8 + lrow) * KB + (size_t)kt * 128 + (lgr << 4),
                sB[buf] + c2 * 1024);
      }
    }
  };
  stage(0, 0);
  int cur = 0;
  for (int kt = 0; kt < nkt; ++kt) {
    __syncthreads();
    if (kt + 1 < nkt) stage(cur ^ 1, kt + 1);
    __builtin_amdgcn_s_setprio(1);
#pragma unroll
    for (int ks = 0; ks < 2; ++ks) {
      FragU af[AM], bfr[AN];
      const int g = ks * 4 + u;
#pragma unroll
      for (int i = 0; i < AM; ++i)
        af[i] = ldfrag(sA[cur], wr * (AM * 16) + i * 16 + r16, g);
#pragma unroll
      for (int i = 0; i < AN; ++i)
        bfr[i] = ldfrag(sB[cur], wc * (AN * 16) + i * 16 + r16, g);
#pragma unroll
      for (int mi = 0; mi < AM; ++mi)
#pragma unroll
        for (int ni = 0; ni < AN; ++ni)
          acc[mi][ni] = __builtin_amdgcn_mfma_f32_16x16x32_bf16(af[mi].b, bfr[ni].b,
                                                                acc[mi][ni], 0, 0, 0);
    }
    __builtin_amdgcn_s_setprio(0);
    cur ^= 1;
  }
  const int row0 = tm * TM + wr * (AM * 16) + (u << 2);
  const int col0 = tn * TN + wc * (AN * 16) + r16;
#pragma unroll
  for (int mi = 0; mi < AM; ++mi) {
#pragma unroll
    for (int ni = 0; ni < AN; ++ni) {
      const int col = col0 + ni * 16;
      if (EPI == EPI_RES) {
#pragma unroll
        for (int r = 0; r < 4; ++r) {
          const int row = row0 + mi * 16 + r;
          outF[(size_t)row * N + col] = acc[mi][ni][r] + bias[col] + res[(size_t)row * N + col];
        }
      } else if (EPI == EPI_GELU) {
#pragma unroll
        for (int r = 0; r < 4; ++r) {
          const int row = row0 + mi * 16 + r;
          const float x = acc[mi][ni][r] + bias[col];
          *(u16*)(outB + gaddr(row, 2 * col, 2 * N)) =
              f2b(0.5f * x * (1.f + erff(x * 0.70710678118f)));
        }
      } else {  // EPI_QKV
        const int which = col >> 9, cc = col & 511;
        const int h = cc >> 6, hd = cc & 63;
        if (which == 2) {                       // V -> [bh] tiled [n/64][hd-row][swz] bf16
          const int rowa = row0 + mi * 16;
          const int bb2 = rowa >> 11, nt0 = rowa & 2047;
          const int bh = bb2 * 8 + h;
          const float bvv = bv[cc];
          union { ushort4 s; u64 q; } pk;
          pk.s.x = f2b(acc[mi][ni][0] + bvv);
          pk.s.y = f2b(acc[mi][ni][1] + bvv);
          pk.s.z = f2b(acc[mi][ni][2] + bvv);
          pk.s.w = f2b(acc[mi][ni][3] + bvv);
          *(u64*)(vo + (size_t)bh * 262144 + (size_t)(nt0 >> 6) * 8192 +
                  gaddr(hd, 2 * (nt0 & 63), 128)) = pk.q;
        } else {
#pragma unroll
          for (int r = 0; r < 4; ++r) {
            const int row = row0 + mi * 16 + r;
            const int bb2 = row >> 11, nt = row & 2047;
            const int bh = bb2 * 8 + h;
            if (which == 0)                     // Q: linear, scale = 0.125 * log2(e)
              qo[((size_t)bh * 2048 + nt) * 64 + hd] = f2b((acc[mi][ni][r] + bq[cc]) * 0.18033688f);
            else                                // K -> [bh] tiled [n/64][n-row][swz]
              *(u16*)(ko + (size_t)bh * 262144 + (size_t)(nt >> 6) * 8192 +
                      gaddr(nt & 63, 2 * hd, 128)) = f2b(acc[mi][ni][r] + bk[cc]);
          }
        }
      }
    }
  }
}

// ---------------- attention: split-KV flash, 32 q-cols per wave ----------------
// 4 waves = 2 kvh x 2 qw; each wave holds 2 Q B-frags -> every K/V fragment read
// feeds 2 MFMAs (LDS traffic halved vs 16-q waves). No-max softmax, MFMA row-sum.
__global__ __launch_bounds__(256)
void attn_k(const u16* __restrict__ q, const char* __restrict__ kswz,
            const char* __restrict__ vswz, char* __restrict__ r_out) {
  __shared__ __align__(16) char sK[2][2][8192];   // [kvh][buf]
  __shared__ __align__(16) char sV[2][2][8192];
  const int tid = threadIdx.x;
  const int l = tid & 63, w = tid >> 6;
  const int kvh = w & 1, qw = w >> 1;
  const int bh = blockIdx.x, qt = blockIdx.y;     // bh on x: same-head blocks share XCD
  const int u = l >> 4, r16 = l & 15;
  const char* kp = kswz + (size_t)bh * 262144;
  const char* vp = vswz + (size_t)bh * 262144;
  // per kvh: 2 waves (qw 0/1) stage 8KB K + 8KB V: each wave 4KB of each
  auto stage = [&](int buf, int t) {
#pragma unroll
    for (int c = 0; c < 4; ++c) {
      gload16(kp + (size_t)t * 8192 + qw * 4096 + c * 1024 + l * 16,
              sK[kvh][buf] + qw * 4096 + c * 1024);
      gload16(vp + (size_t)t * 8192 + qw * 4096 + c * 1024 + l * 16,
              sV[kvh][buf] + qw * 4096 + c * 1024);
    }
  };
  stage(0, kvh * 16);
  FragU qf[2][2], ones;   // [f][ks]
  {
#pragma unroll
    for (int f = 0; f < 2; ++f) {
      const u16* qr = q + (size_t)bh * (2048 * 64) +
                      (size_t)(qt * 64 + qw * 32 + f * 16 + r16) * 64 + (u << 2);
      qf[f][0].u[0] = *(const u64*)qr;        qf[f][0].u[1] = *(const u64*)(qr + 16);
      qf[f][1].u[0] = *(const u64*)(qr + 32); qf[f][1].u[1] = *(const u64*)(qr + 48);
    }
    ones.u[0] = 0x3F803F803F803F80ull;   // 4 x bf16(1.0)
    ones.u[1] = 0x3F803F803F803F80ull;
  }
  f32x4 o[4][2] = {};
  f32x4 lacc[2] = {};
  int cur = 0;
  for (int i = 0; i < 16; ++i) {
    __syncthreads();
    if (i < 15) stage(cur ^ 1, kvh * 16 + i + 1);
    f32x4 st[4][2] = {};
    __builtin_amdgcn_s_setprio(1);
#pragma unroll
    for (int ks = 0; ks < 2; ++ks) {
      const int g = ks * 4 + u;
#pragma unroll
      for (int mi = 0; mi < 4; ++mi) {
        const FragU kf = ldfrag(sK[kvh][cur], mi * 16 + r16, g);
#pragma unroll
        for (int f = 0; f < 2; ++f)
          st[mi][f] = __builtin_amdgcn_mfma_f32_16x16x32_bf16(kf.b, qf[f][ks].b,
                                                              st[mi][f], 0, 0, 0);
      }
    }
    __builtin_amdgcn_s_setprio(0);
    // no-max softmax: P = exp2(S) in place
#pragma unroll
    for (int mi = 0; mi < 4; ++mi)
#pragma unroll
      for (int f = 0; f < 2; ++f)
#pragma unroll
        for (int r = 0; r < 4; ++r) st[mi][f][r] = exp2a(st[mi][f][r]);
    FragU pb[2][2];   // [f][ks]
#pragma unroll
    for (int f = 0; f < 2; ++f)
#pragma unroll
      for (int ks = 0; ks < 2; ++ks)
#pragma unroll
        for (int j = 0; j < 4; ++j) {
          pb[f][ks].e[j]     = (__bf16)st[2 * ks][f][j];
          pb[f][ks].e[j + 4] = (__bf16)st[2 * ks + 1][f][j];
        }
    __builtin_amdgcn_s_setprio(1);
#pragma unroll
    for (int ks = 0; ks < 2; ++ks) {
      const int g = ks * 4 + u;
#pragma unroll
      for (int f = 0; f < 2; ++f)
        lacc[f] = __builtin_amdgcn_mfma_f32_16x16x32_bf16(ones.b, pb[f][ks].b, lacc[f], 0, 0, 0);
#pragma unroll
      for (int mo = 0; mo < 4; ++mo) {
        const FragU vf = ldfrag(sV[kvh][cur], mo * 16 + r16, g);
#pragma unroll
        for (int f = 0; f < 2; ++f)
          o[mo][f] = __builtin_amdgcn_mfma_f32_16x16x32_bf16(vf.b, pb[f][ks].b,
                                                             o[mo][f], 0, 0, 0);
      }
    }
    __builtin_amdgcn_s_setprio(0);
    cur ^= 1;
  }
  // ---- combine the two KV halves via LDS (no max: just add O and l) ----
  __syncthreads();
  float* scrO = (float*)&sK[0][0][0];   // 2 qw x 64 hd x 32 q = 16KB
  float* scrL = (float*)&sV[0][0][0];   // 2 qw x 32
  if (kvh == 1) {
    if (u == 0)
#pragma unroll
      for (int f = 0; f < 2; ++f) scrL[qw * 32 + f * 16 + r16] = lacc[f][0];
#pragma unroll
    for (int mo = 0; mo < 4; ++mo)
#pragma unroll
      for (int f = 0; f < 2; ++f)
#pragma unroll
        for (int r = 0; r < 4; ++r)
          scrO[qw * 2048 + (mo * 16 + u * 4 + r) * 32 + f * 16 + r16] = o[mo][f][r];
  }
  __syncthreads();
  if (kvh == 0) {
    const int h = bh & 7;
#pragma unroll
    for (int f = 0; f < 2; ++f) {
      const float linv = 1.f / (lacc[f][0] + scrL[qw * 32 + f * 16 + r16]);
      const int tok = (bh >> 3) * 2048 + qt * 64 + qw * 32 + f * 16 + r16;
#pragma unroll
      for (int mo = 0; mo < 4; ++mo) {
        union { ushort4 s; u64 qq; } pk;
        float vv[4];
#pragma unroll
        for (int r = 0; r < 4; ++r)
          vv[r] = (o[mo][f][r] + scrO[qw * 2048 + (mo * 16 + u * 4 + r) * 32 + f * 16 + r16]) * linv;
        pk.s.x = f2b(vv[0]); pk.s.y = f2b(vv[1]); pk.s.z = f2b(vv[2]); pk.s.w = f2b(vv[3]);
        *(u64*)(r_out + (size_t)tok * 1024 + h * 128 + swzo(tok, mo * 32 + (u << 3))) = pk.qq;
      }
    }
  }
}

// ---------------- launch ----------------
extern "C" void kernel_launch(void* const* d_in, const int* in_sizes, int n_in,
                              void* d_out, int out_size, void* d_ws, size_t ws_size,
                              hipStream_t stream) {
  const float* y    = (const float*)d_in[0];
  const float* Wq   = (const float*)d_in[1];
  const float* bq   = (const float*)d_in[2];
  const float* Wk   = (const float*)d_in[3];
  const float* bk   = (const float*)d_in[4];
  const float* Wv   = (const float*)d_in[5];
  const float* bv   = (const float*)d_in[6];
  const float* Wo   = (const float*)d_in[7];
  const float* bo   = (const float*)d_in[8];
  const float* ln1g = (const float*)d_in[9];
  const float* ln1b = (const float*)d_in[10];
  const float* ln2g = (const float*)d_in[11];
  const float* ln2b = (const float*)d_in[12];
  const float* W1   = (const float*)d_in[13];
  const float* b1   = (const float*)d_in[14];
  const float* W2   = (const float*)d_in[15];
  const float* b2   = (const float*)d_in[16];
  float* out = (float*)d_out;
  char* ws = (char*)d_ws;
  char* xb    = ws;                         // 4 MiB LN out (swizzled A)
  u16*  qb    = (u16*)(ws + (4u << 20));    // 4 MiB Q linear
  char* kswz  = ws + (8u << 20);            // 4 MiB K tiled+swizzled
  char* vswz  = ws + (12u << 20);           // 4 MiB V^T tiled+swizzled
  char* rb    = ws + (16u << 20);           // 4 MiB attn out (swizzled A)
  char* g1b   = ws + (20u << 20);           // 8 MiB gelu out (swizzled A)
  u16* wqkvT  = (u16*)(ws + (28u << 20));   // [1536][512] swizzled
  u16* woT    = wqkvT + 1536 * 512;
  u16* w1T    = woT + 512 * 512;
  u16* w2T    = w1T + 1024 * 512;

  prep<<<6144, 256, 0, stream>>>(Wq, Wk, Wv, Wo, W1, W2, wqkvT, woT, w1T, w2T,
                                 y, ln1g, ln1b, xb);
  gemm_bf16<EPI_QKV, 2, 2, 4, 2><<<dim3(32, 24), 256, 0, stream>>>(
      xb, (const char*)wqkvT, 1536, 512, nullptr, bq, bk, bv,
      nullptr, nullptr, nullptr, qb, kswz, vswz);
  attn_k<<<dim3(16, 32), 256, 0, stream>>>(qb, kswz, vswz, rb);
  gemm_bf16<EPI_RES, 2, 2, 2, 2><<<dim3(64, 8), 256, 0, stream>>>(
      rb, (const char*)woT, 512, 512, bo, nullptr, nullptr, nullptr,
      y, out, nullptr, nullptr, nullptr, nullptr);
  ln_bf16<<<4096, 256, 0, stream>>>(out, ln2g, ln2b, xb);
  gemm_bf16<EPI_GELU, 2, 2, 4, 4><<<dim3(32, 8), 256, 0, stream>>>(
      xb, (const char*)w1T, 1024, 512, b1, nullptr, nullptr, nullptr,
      nullptr, nullptr, g1b, nullptr, nullptr, nullptr);
  gemm_bf16<EPI_RES, 2, 2, 2, 2><<<dim3(64, 8), 256, 0, stream>>>(
      g1b, (const char*)w2T, 512, 1024, b2, nullptr, nullptr, nullptr,
      out, out, nullptr, nullptr, nullptr, nullptr);
}

// Round 12
// 90.537 us; speedup vs baseline: 1.0869x; 1.0869x over previous
//
#include <hip/hip_runtime.h>

#define DEVI __device__ __forceinline__

typedef unsigned short u16;
typedef unsigned int   u32;
typedef unsigned long long u64;
typedef float  f32x4  __attribute__((ext_vector_type(4)));
typedef __bf16 bf16x8 __attribute__((ext_vector_type(8)));

union FragU { bf16x8 b; u64 u[2]; __bf16 e[8]; };

DEVI u16 f2b(float x) { __bf16 t = (__bf16)x; return __builtin_bit_cast(u16, t); }

DEVI float exp2a(float x) { float r; asm("v_exp_f32 %0, %1" : "=v"(r) : "v"(x)); return r; }

DEVI void gload16(const void* g, void* l) {
  __builtin_amdgcn_global_load_lds((const __attribute__((address_space(1))) u32*)g,
                                   (__attribute__((address_space(3))) u32*)l, 16, 0, 0);
}

// k-bit-permutation within a 128B chunk: makes MFMA fragment (ks,u) bytes contiguous.
// old bits [6]=ks [5]=hi [4:3]=u [2:0]=lo  ->  new: ks | u<<4 | hi<<3 | lo
DEVI int kperm(int b) {
  return (b & 0x47) | ((b & 0x18) << 1) | ((b & 0x20) >> 2);
}
// producer-side swizzled offset within one [row][128B] chunk: perm + granule XOR
DEVI int swzo(int row, int b) {
  const int p = kperm(b);
  return ((((p >> 4) ^ row) & 7) << 4) | (p & 15);
}
// consumer: single ds_read_b128 of fragment granule g = ks*4+u
DEVI FragU ldfrag(const char* base, int row, int g) {
  return *reinterpret_cast<const FragU*>(base + row * 128 + (((g ^ (row & 7)) << 4)));
}
// 64B-chunk variant (V tiles: 32-kv chunks): granule g = u, XOR with row&3
DEVI FragU ldfrag64(const char* base, int row, int g) {
  return *reinterpret_cast<const FragU*>(base + row * 64 + (((g ^ (row & 3)) << 4)));
}
// producer-side global address: linear rows of `rowbytes`, swizzled within each 128B chunk
DEVI size_t gaddr(int row, int kbyte, int rowbytes) {
  return (size_t)row * rowbytes + (size_t)((kbyte & ~127) + swzo(row, kbyte & 127));
}

// ---------------- prep: 6 weight transposes + LN1, one kernel ----------------
__global__ __launch_bounds__(256)
void prep(const float* __restrict__ Wq, const float* __restrict__ Wk,
          const float* __restrict__ Wv, const float* __restrict__ Wo,
          const float* __restrict__ W1, const float* __restrict__ W2,
          u16* __restrict__ wqkvT, u16* __restrict__ woT,
          u16* __restrict__ w1T, u16* __restrict__ w2T,
          const float* __restrict__ y, const float* __restrict__ ln1g,
          const float* __restrict__ ln1b, char* __restrict__ xb) {
  const int id = blockIdx.x;
  if (id < 2048) {
    __shared__ float tile[32][33];
    const float* src; u16* dst; int K, N, bx, by;
    if (id < 1024) {
      const int m = id >> 8, t = id & 255;
      K = 512; N = 512; bx = t & 15; by = t >> 4;
      src = (m == 0) ? Wq : (m == 1) ? Wk : (m == 2) ? Wv : Wo;
      dst = (m == 3) ? woT : wqkvT + m * 512 * 512;
    } else if (id < 1536) {
      const int t = id - 1024; K = 512; N = 1024; bx = t & 31; by = t >> 5;
      src = W1; dst = w1T;
    } else {
      const int t = id - 1536; K = 1024; N = 512; bx = t & 15; by = t >> 4;
      src = W2; dst = w2T;
    }
    const int tx = threadIdx.x & 31, ty = threadIdx.x >> 5;
#pragma unroll
    for (int i = 0; i < 4; ++i)
      tile[ty + i * 8][tx] = src[(size_t)(by * 32 + ty + i * 8) * N + bx * 32 + tx];
    __syncthreads();
    // write side: thread packs 4 consecutive k into one swizzled u64 store
    const int nl = threadIdx.x >> 3, kq = threadIdx.x & 7;
    const int n = bx * 32 + nl;
    const int kg = by * 32 + kq * 4;
    union { ushort4 s; u64 q; } pk;
    pk.s.x = f2b(tile[kq * 4 + 0][nl]);
    pk.s.y = f2b(tile[kq * 4 + 1][nl]);
    pk.s.z = f2b(tile[kq * 4 + 2][nl]);
    pk.s.w = f2b(tile[kq * 4 + 3][nl]);
    *(u64*)((char*)dst + gaddr(n, 2 * kg, 2 * K)) = pk.q;
  } else {
    const int row = id - 2048;
    const int t = threadIdx.x;
    const float2 v = ((const float2*)(y + (size_t)row * 512))[t];
    float s1 = v.x + v.y, s2 = v.x * v.x + v.y * v.y;
#pragma unroll
    for (int off = 32; off; off >>= 1) { s1 += __shfl_xor(s1, off); s2 += __shfl_xor(s2, off); }
    __shared__ float a1[4], a2[4];
    const int w = t >> 6;
    if ((t & 63) == 0) { a1[w] = s1; a2[w] = s2; }
    __syncthreads();
    s1 = a1[0] + a1[1] + a1[2] + a1[3];
    s2 = a2[0] + a2[1] + a2[2] + a2[3];
    const float mean = s1 * (1.f / 512.f);
    const float var = s2 * (1.f / 512.f) - mean * mean;
    const float rstd = rsqrtf(var + 1e-5f);
    const float2 gg = ((const float2*)ln1g)[t];
    const float2 bb = ((const float2*)ln1b)[t];
    const u16 o0 = f2b((v.x - mean) * rstd * gg.x + bb.x);
    const u16 o1 = f2b((v.y - mean) * rstd * gg.y + bb.y);
    *(u32*)(xb + gaddr(row, 4 * t, 1024)) = (u32)o0 | ((u32)o1 << 16);
  }
}

// ---------------- layernorm f32 -> bf16 (swizzled output), row = 512 ----------------
__global__ __launch_bounds__(256)
void ln_bf16(const float* __restrict__ x, const float* __restrict__ g,
             const float* __restrict__ b, char* __restrict__ out) {
  const int row = blockIdx.x;
  const int t = threadIdx.x;
  const float2 v = ((const float2*)(x + (size_t)row * 512))[t];
  float s1 = v.x + v.y, s2 = v.x * v.x + v.y * v.y;
#pragma unroll
  for (int off = 32; off; off >>= 1) { s1 += __shfl_xor(s1, off); s2 += __shfl_xor(s2, off); }
  __shared__ float a1[4], a2[4];
  const int w = t >> 6;
  if ((t & 63) == 0) { a1[w] = s1; a2[w] = s2; }
  __syncthreads();
  s1 = a1[0] + a1[1] + a1[2] + a1[3];
  s2 = a2[0] + a2[1] + a2[2] + a2[3];
  const float mean = s1 * (1.f / 512.f);
  const float var = s2 * (1.f / 512.f) - mean * mean;
  const float rstd = rsqrtf(var + 1e-5f);
  const float2 gg = ((const float2*)g)[t];
  const float2 bb = ((const float2*)b)[t];
  const u16 o0 = f2b((v.x - mean) * rstd * gg.x + bb.x);
  const u16 o1 = f2b((v.y - mean) * rstd * gg.y + bb.y);
  *(u32*)(out + gaddr(row, 4 * t, 1024)) = (u32)o0 | ((u32)o1 << 16);
}

// ---------------- GEMM: C = A[M][K] @ Bt[N][K]^T ----------------
enum { EPI_QKV = 0, EPI_RES = 1, EPI_GELU = 2 };

template <int EPI, int WM, int WN, int AM, int AN>
__global__ __launch_bounds__(WM * WN * 64)
void gemm_bf16(const char* __restrict__ A, const char* __restrict__ Bt, int N, int K,
               const float* __restrict__ bias,
               const float* __restrict__ bq, const float* __restrict__ bk,
               const float* __restrict__ bv,
               const float* __restrict__ res, float* __restrict__ outF,
               char* __restrict__ outB,
               u16* __restrict__ qo, char* __restrict__ ko, char* __restrict__ vo) {
  constexpr int NW = WM * WN;
  constexpr int TM = WM * AM * 16, TN = WN * AN * 16;
  constexpr int NCHA = TM / 8, NCHB = TN / 8, NCH = NCHA + NCHB;
  constexpr int CPW = NCH / NW;
  static_assert(CPW * NW == NCH, "chunk split");
  __shared__ __align__(16) char sA[2][TM * 128];
  __shared__ __align__(16) char sB[2][TN * 128];
  const int tid = threadIdx.x;
  const int l = tid & 63, w = tid >> 6;
  const int tm = blockIdx.x, tn = blockIdx.y;
  const int wr = w / WN, wc = w % WN;
  const int u = l >> 4, r16 = l & 15;
  const int lrow = l >> 3, lgr = l & 7;
  f32x4 acc[AM][AN] = {};
  const size_t KB = (size_t)K * 2;
  const char* Ab = A + (size_t)(tm * TM) * KB;
  const char* Bb = Bt + (size_t)(tn * TN) * KB;
  const int nkt = K >> 6;
  auto stage = [&](int buf, int kt) {
#pragma unroll
    for (int i = 0; i < CPW; ++i) {
      const int c = w * CPW + i;
      if (c < NCHA) {
        gload16(Ab + (size_t)(c * 8 + lrow) * KB + (size_t)kt * 128 + (lgr << 4),
                sA[buf] + c * 1024);
      } else {
        const int c2 = c - NCHA;
        gload16(Bb + (size_t)(c2 * 8 + lrow) * KB + (size_t)kt * 128 + (lgr << 4),
                sB[buf] + c2 * 1024);
      }
    }
  };
  stage(0, 0);
  int cur = 0;
  for (int kt = 0; kt < nkt; ++kt) {
    __syncthreads();
    if (kt + 1 < nkt) stage(cur ^ 1, kt + 1);
    __builtin_amdgcn_s_setprio(1);
#pragma unroll
    for (int ks = 0; ks < 2; ++ks) {
      FragU af[AM], bfr[AN];
      const int g = ks * 4 + u;
#pragma unroll
      for (int i = 0; i < AM; ++i)
        af[i] = ldfrag(sA[cur], wr * (AM * 16) + i * 16 + r16, g);
#pragma unroll
      for (int i = 0; i < AN; ++i)
        bfr[i] = ldfrag(sB[cur], wc * (AN * 16) + i * 16 + r16, g);
#pragma unroll
      for (int mi = 0; mi < AM; ++mi)
#pragma unroll
        for (int ni = 0; ni < AN; ++ni)
          acc[mi][ni] = __builtin_amdgcn_mfma_f32_16x16x32_bf16(af[mi].b, bfr[ni].b,
                                                                acc[mi][ni], 0, 0, 0);
    }
    __builtin_amdgcn_s_setprio(0);
    cur ^= 1;
  }
  const int row0 = tm * TM + wr * (AM * 16) + (u << 2);
  const int col0 = tn * TN + wc * (AN * 16) + r16;
#pragma unroll
  for (int mi = 0; mi < AM; ++mi) {
#pragma unroll
    for (int ni = 0; ni < AN; ++ni) {
      const int col = col0 + ni * 16;
      if (EPI == EPI_RES) {
#pragma unroll
        for (int r = 0; r < 4; ++r) {
          const int row = row0 + mi * 16 + r;
          outF[(size_t)row * N + col] = acc[mi][ni][r] + bias[col] + res[(size_t)row * N + col];
        }
      } else if (EPI == EPI_GELU) {
#pragma unroll
        for (int r = 0; r < 4; ++r) {
          const int row = row0 + mi * 16 + r;
          const float x = acc[mi][ni][r] + bias[col];
          *(u16*)(outB + gaddr(row, 2 * col, 2 * N)) =
              f2b(0.5f * x * (1.f + erff(x * 0.70710678118f)));
        }
      } else {  // EPI_QKV
        const int which = col >> 9, cc = col & 511;
        const int h = cc >> 6, hd = cc & 63;
        if (which == 2) {                       // V -> [bh][n/32 tile][hd row][64B kperm] bf16
          const int rowa = row0 + mi * 16;
          const int bb2 = rowa >> 11, nt0 = rowa & 2047;
          const int bh = bb2 * 8 + h;
          const float bvv = bv[cc];
          union { ushort4 s; u64 q; } pk;
          pk.s.x = f2b(acc[mi][ni][0] + bvv);
          pk.s.y = f2b(acc[mi][ni][1] + bvv);
          pk.s.z = f2b(acc[mi][ni][2] + bvv);
          pk.s.w = f2b(acc[mi][ni][3] + bvv);
          const int kl = nt0 & 31;
          const int off64 = ((((kl >> 2) & 3) ^ (hd & 3)) << 4) | (((kl >> 4) & 1) << 3);
          *(u64*)(vo + (size_t)bh * 262144 + (size_t)(nt0 >> 5) * 4096 + hd * 64 + off64) = pk.q;
        } else {
#pragma unroll
          for (int r = 0; r < 4; ++r) {
            const int row = row0 + mi * 16 + r;
            const int bb2 = row >> 11, nt = row & 2047;
            const int bh = bb2 * 8 + h;
            if (which == 0)                     // Q: linear, scale = 0.125 * log2(e)
              qo[((size_t)bh * 2048 + nt) * 64 + hd] = f2b((acc[mi][ni][r] + bq[cc]) * 0.18033688f);
            else                                // K -> [bh] tiled [n/64][n-row][swz]
              *(u16*)(ko + (size_t)bh * 262144 + (size_t)(nt >> 6) * 8192 +
                      gaddr(nt & 63, 2 * hd, 128)) = f2b(acc[mi][ni][r] + bk[cc]);
          }
        }
      }
    }
  }
}

// ---------------- attention: 4-way split-KV, 32 q-cols per wave, 32-kv tiles ----------------
// 8 waves = 4 kvh x 2 qw. Each K/V fragment read feeds 2 MFMAs (q-sharing) while
// keeping 16 waves/CU (64KB LDS, <=128 VGPR). K tiles: contiguous 4KB halves of the
// 128B-chunk layout. V tiles: dedicated 64B-chunk layout. No-max softmax, MFMA row-sum.
__global__ __launch_bounds__(512, 4)
void attn_k(const u16* __restrict__ q, const char* __restrict__ kswz,
            const char* __restrict__ vswz, char* __restrict__ r_out) {
  __shared__ __align__(16) char smem[65536];
  char (*sK)[2][4096] = (char(*)[2][4096])smem;            // [4][2][4096]
  char (*sV)[2][4096] = (char(*)[2][4096])(smem + 32768);  // [4][2][4096]
  const int tid = threadIdx.x;
  const int l = tid & 63, w = tid >> 6;
  const int kvh = w & 3, qw = w >> 2;
  const int bh = blockIdx.x, qt = blockIdx.y;     // bh on x: same-head blocks share XCD
  const int u = l >> 4, r16 = l & 15;
  const char* kp = kswz + (size_t)bh * 262144;
  const char* vp = vswz + (size_t)bh * 262144;
  auto stage = [&](int buf, int i) {
    const int t32 = kvh * 16 + i;
    const size_t koff = (size_t)(t32 >> 1) * 8192 + (size_t)(t32 & 1) * 4096;
    const size_t voff = (size_t)t32 * 4096;
#pragma unroll
    for (int c = 0; c < 2; ++c) {
      gload16(kp + koff + qw * 2048 + c * 1024 + l * 16, sK[kvh][buf] + qw * 2048 + c * 1024);
      gload16(vp + voff + qw * 2048 + c * 1024 + l * 16, sV[kvh][buf] + qw * 2048 + c * 1024);
    }
  };
  stage(0, 0);
  FragU qf[2][2], ones;   // [f][ks]
  {
#pragma unroll
    for (int f = 0; f < 2; ++f) {
      const u16* qr = q + (size_t)bh * (2048 * 64) +
                      (size_t)(qt * 64 + qw * 32 + f * 16 + r16) * 64 + (u << 2);
      qf[f][0].u[0] = *(const u64*)qr;        qf[f][0].u[1] = *(const u64*)(qr + 16);
      qf[f][1].u[0] = *(const u64*)(qr + 32); qf[f][1].u[1] = *(const u64*)(qr + 48);
    }
    ones.u[0] = 0x3F803F803F803F80ull;   // 4 x bf16(1.0)
    ones.u[1] = 0x3F803F803F803F80ull;
  }
  f32x4 o[4][2] = {};
  f32x4 lacc[2] = {};
  int cur = 0;
  for (int i = 0; i < 16; ++i) {
    __syncthreads();
    if (i < 15) stage(cur ^ 1, i + 1);
    f32x4 st[2][2] = {};
    __builtin_amdgcn_s_setprio(1);
#pragma unroll
    for (int ks = 0; ks < 2; ++ks) {
      const int g = ks * 4 + u;
#pragma unroll
      for (int mi = 0; mi < 2; ++mi) {
        const FragU kf = ldfrag(sK[kvh][cur], mi * 16 + r16, g);
#pragma unroll
        for (int f = 0; f < 2; ++f)
          st[mi][f] = __builtin_amdgcn_mfma_f32_16x16x32_bf16(kf.b, qf[f][ks].b,
                                                              st[mi][f], 0, 0, 0);
      }
    }
    __builtin_amdgcn_s_setprio(0);
    // no-max softmax: P = exp2(S) in place
#pragma unroll
    for (int mi = 0; mi < 2; ++mi)
#pragma unroll
      for (int f = 0; f < 2; ++f)
#pragma unroll
        for (int r = 0; r < 4; ++r) st[mi][f][r] = exp2a(st[mi][f][r]);
    FragU pb[2];
#pragma unroll
    for (int f = 0; f < 2; ++f)
#pragma unroll
      for (int j = 0; j < 4; ++j) {
        pb[f].e[j]     = (__bf16)st[0][f][j];
        pb[f].e[j + 4] = (__bf16)st[1][f][j];
      }
    __builtin_amdgcn_s_setprio(1);
#pragma unroll
    for (int f = 0; f < 2; ++f)
      lacc[f] = __builtin_amdgcn_mfma_f32_16x16x32_bf16(ones.b, pb[f].b, lacc[f], 0, 0, 0);
#pragma unroll
    for (int mo = 0; mo < 4; ++mo) {
      const FragU vf = ldfrag64(sV[kvh][cur], mo * 16 + r16, u);
#pragma unroll
      for (int f = 0; f < 2; ++f)
        o[mo][f] = __builtin_amdgcn_mfma_f32_16x16x32_bf16(vf.b, pb[f].b, o[mo][f], 0, 0, 0);
    }
    __builtin_amdgcn_s_setprio(0);
    cur ^= 1;
  }
  // ---- combine the 4 KV quarters via LDS (no max: just add O and l) ----
  __syncthreads();
  float* scrO = (float*)smem;              // 3 grp x 2 qw x 2048 floats = 48KB
  float* scrL = (float*)smem + 12288;      // 3 grp x 2 qw x 32 floats
  if (kvh != 0) {
    const int base = ((kvh - 1) * 2 + qw) * 2048;
    if (u == 0)
#pragma unroll
      for (int f = 0; f < 2; ++f)
        scrL[((kvh - 1) * 2 + qw) * 32 + f * 16 + r16] = lacc[f][0];
#pragma unroll
    for (int mo = 0; mo < 4; ++mo)
#pragma unroll
      for (int f = 0; f < 2; ++f)
#pragma unroll
        for (int r = 0; r < 4; ++r)
          scrO[base + (mo * 16 + u * 4 + r) * 32 + f * 16 + r16] = o[mo][f][r];
  }
  __syncthreads();
  if (kvh == 0) {
    const int h = bh & 7;
#pragma unroll
    for (int f = 0; f < 2; ++f) {
      float lsum = lacc[f][0];
#pragma unroll
      for (int g2 = 0; g2 < 3; ++g2)
        lsum += scrL[(g2 * 2 + qw) * 32 + f * 16 + r16];
      const float linv = 1.f / lsum;
      const int tok = (bh >> 3) * 2048 + qt * 64 + qw * 32 + f * 16 + r16;
#pragma unroll
      for (int mo = 0; mo < 4; ++mo) {
        union { ushort4 s; u64 qq; } pk;
        float vv[4];
#pragma unroll
        for (int r = 0; r < 4; ++r) {
          float acc2 = o[mo][f][r];
#pragma unroll
          for (int g2 = 0; g2 < 3; ++g2)
            acc2 += scrO[(g2 * 2 + qw) * 2048 + (mo * 16 + u * 4 + r) * 32 + f * 16 + r16];
          vv[r] = acc2 * linv;
        }
        pk.s.x = f2b(vv[0]); pk.s.y = f2b(vv[1]); pk.s.z = f2b(vv[2]); pk.s.w = f2b(vv[3]);
        *(u64*)(r_out + (size_t)tok * 1024 + h * 128 + swzo(tok, mo * 32 + (u << 3))) = pk.qq;
      }
    }
  }
}

// ---------------- launch ----------------
extern "C" void kernel_launch(void* const* d_in, const int* in_sizes, int n_in,
                              void* d_out, int out_size, void* d_ws, size_t ws_size,
                              hipStream_t stream) {
  const float* y    = (const float*)d_in[0];
  const float* Wq   = (const float*)d_in[1];
  const float* bq   = (const float*)d_in[2];
  const float* Wk   = (const float*)d_in[3];
  const float* bk   = (const float*)d_in[4];
  const float* Wv   = (const float*)d_in[5];
  const float* bv   = (const float*)d_in[6];
  const float* Wo   = (const float*)d_in[7];
  const float* bo   = (const float*)d_in[8];
  const float* ln1g = (const float*)d_in[9];
  const float* ln1b = (const float*)d_in[10];
  const float* ln2g = (const float*)d_in[11];
  const float* ln2b = (const float*)d_in[12];
  const float* W1   = (const float*)d_in[13];
  const float* b1   = (const float*)d_in[14];
  const float* W2   = (const float*)d_in[15];
  const float* b2   = (const float*)d_in[16];
  float* out = (float*)d_out;
  char* ws = (char*)d_ws;
  char* xb    = ws;                         // 4 MiB LN out (swizzled A)
  u16*  qb    = (u16*)(ws + (4u << 20));    // 4 MiB Q linear
  char* kswz  = ws + (8u << 20);            // 4 MiB K tiled+swizzled (64-row tiles)
  char* vswz  = ws + (12u << 20);           // 4 MiB V (32-kv 64B-chunk tiles)
  char* rb    = ws + (16u << 20);           // 4 MiB attn out (swizzled A)
  char* g1b   = ws + (20u << 20);           // 8 MiB gelu out (swizzled A)
  u16* wqkvT  = (u16*)(ws + (28u << 20));   // [1536][512] swizzled
  u16* woT    = wqkvT + 1536 * 512;
  u16* w1T    = woT + 512 * 512;
  u16* w2T    = w1T + 1024 * 512;

  prep<<<6144, 256, 0, stream>>>(Wq, Wk, Wv, Wo, W1, W2, wqkvT, woT, w1T, w2T,
                                 y, ln1g, ln1b, xb);
  gemm_bf16<EPI_QKV, 2, 2, 4, 2><<<dim3(32, 24), 256, 0, stream>>>(
      xb, (const char*)wqkvT, 1536, 512, nullptr, bq, bk, bv,
      nullptr, nullptr, nullptr, qb, kswz, vswz);
  attn_k<<<dim3(16, 32), 512, 0, stream>>>(qb, kswz, vswz, rb);
  gemm_bf16<EPI_RES, 2, 2, 2, 2><<<dim3(64, 8), 256, 0, stream>>>(
      rb, (const char*)woT, 512, 512, bo, nullptr, nullptr, nullptr,
      y, out, nullptr, nullptr, nullptr, nullptr);
  ln_bf16<<<4096, 256, 0, stream>>>(out, ln2g, ln2b, xb);
  gemm_bf16<EPI_GELU, 2, 2, 4, 2><<<dim3(32, 16), 256, 0, stream>>>(
      xb, (const char*)w1T, 1024, 512, b1, nullptr, nullptr, nullptr,
      nullptr, nullptr, g1b, nullptr, nullptr, nullptr);
  gemm_bf16<EPI_RES, 2, 2, 2, 2><<<dim3(64, 8), 256, 0, stream>>>(
      g1b, (const char*)w2T, 512, 1024, b2, nullptr, nullptr, nullptr,
      out, out, nullptr, nullptr, nullptr, nullptr);
}